// Round 1
// baseline (101.663 us; speedup 1.0000x reference)
//
#include <hip/hip_runtime.h>

typedef __attribute__((ext_vector_type(8))) short bf16x8;
typedef __attribute__((ext_vector_type(4))) float f32x4;
typedef __attribute__((ext_vector_type(4))) unsigned short u16x4;
typedef __attribute__((ext_vector_type(8))) unsigned short u16x8;

#define MFMA(a, b, c) __builtin_amdgcn_mfma_f32_16x16x32_bf16(a, b, c, 0, 0, 0)

static __device__ __forceinline__ unsigned short f2bf(float x) {
    union { float f; unsigned u; } v; v.f = x;
    unsigned r = v.u + 0x7fffu + ((v.u >> 16) & 1u);   // round-to-nearest-even
    return (unsigned short)(r >> 16);
}

// ---------------- Kernel 0: W [1024][64] f32 -> Wt [3][64][1024] bf16 ----------------
__global__ __launch_bounds__(256) void wtrans_k(
    const float* __restrict__ Wk, const float* __restrict__ Wq,
    const float* __restrict__ Wv, unsigned short* __restrict__ Wt)
{
    int id = blockIdx.x * 256 + threadIdx.x;          // < 3*65536
    int w = id >> 16, rem = id & 65535;
    int n = rem >> 10, k = rem & 1023;
    const float* W = (w == 0) ? Wk : (w == 1) ? Wq : Wv;
    Wt[id] = f2bf(W[k * 64 + n]);                     // writes coalesced, reads L2-absorbed
}

// ---------------- Kernel 1: QKV projection ----------------
// x [16384][1024] f32, Wt [192][1024] bf16 (K,Q,V stacked)
// -> Kb [16384][64], Qb [16384][64], Vt [8][64][2048]   (all bf16)
__global__ __launch_bounds__(256) void qkv_k(
    const float* __restrict__ x, const unsigned short* __restrict__ Wt,
    unsigned short* __restrict__ Qb, unsigned short* __restrict__ Kb,
    unsigned short* __restrict__ Vt)
{
    __shared__ __align__(16) unsigned short xl[32][72];    // +8 pad: stride 144B, 2-way only
    __shared__ __align__(16) unsigned short wl[192][72];
    const int tid = threadIdx.x;
    const int wid = tid >> 6, lane = tid & 63;
    const int lrow = lane & 15, g = lane >> 4;
    const int mbase = blockIdx.x * 32;
    const int msrow = (wid & 1) * 16;        // wave's 16-row m-subtile
    const int ntbase = (wid >> 1) * 6;       // wave's 6 n-tiles (of 12)

    f32x4 acc[6];
#pragma unroll
    for (int j = 0; j < 6; j++) acc[j] = (f32x4){0.f, 0.f, 0.f, 0.f};

    for (int kc = 0; kc < 1024; kc += 64) {
        // stage x chunk [32][64] f32 -> bf16 (coalesced float4 loads)
#pragma unroll
        for (int rep = 0; rep < 2; rep++) {
            int flat = rep * 256 + tid;                 // 0..511
            int row = flat >> 4, c4 = (flat & 15) * 4;
            f32x4 v = *(const f32x4*)(x + (mbase + row) * 1024 + kc + c4);
            u16x4 h;
            h[0] = f2bf(v[0]); h[1] = f2bf(v[1]); h[2] = f2bf(v[2]); h[3] = f2bf(v[3]);
            *(u16x4*)&xl[row][c4] = h;
        }
        // stage W chunk [192][64] bf16 (16B coalesced)
#pragma unroll
        for (int rep = 0; rep < 6; rep++) {
            int flat = rep * 256 + tid;                 // 0..1535
            int n = flat >> 3, c = (flat & 7) * 8;
            *(u16x8*)&wl[n][c] = *(const u16x8*)(Wt + n * 1024 + kc + c);
        }
        __syncthreads();
#pragma unroll
        for (int ks = 0; ks < 2; ks++) {
            bf16x8 a = *(const bf16x8*)&xl[msrow + lrow][ks * 32 + g * 8];
#pragma unroll
            for (int j = 0; j < 6; j++) {
                bf16x8 b = *(const bf16x8*)&wl[(ntbase + j) * 16 + lrow][ks * 32 + g * 8];
                acc[j] = MFMA(a, b, acc[j]);
            }
        }
        __syncthreads();
    }

    // epilogue: D layout col=lane&15, row=(lane>>4)*4+reg
#pragma unroll
    for (int j = 0; j < 6; j++) {
        int nt = ntbase + j;
        int w = nt >> 2;                                // 0=K, 1=Q, 2=V
        int col = (nt & 3) * 16 + lrow;                 // head dim 0..63
        int r0 = mbase + msrow + g * 4;                 // 4 consecutive token rows
        if (w == 2) {
            int b = r0 >> 11, t = r0 & 2047;            // blocks never straddle batches
            u16x4 pv;
            pv[0] = f2bf(acc[j][0]); pv[1] = f2bf(acc[j][1]);
            pv[2] = f2bf(acc[j][2]); pv[3] = f2bf(acc[j][3]);
            *(u16x4*)(Vt + b * 131072 + col * 2048 + t) = pv;   // transposed V
        } else {
            unsigned short* dst = (w == 0) ? Kb : Qb;
#pragma unroll
            for (int i = 0; i < 4; i++)
                dst[(r0 + i) * 64 + col] = f2bf(acc[j][i]);
        }
    }
}

// ---------------- Kernel 2: causal flash attention ----------------
// Qb/Kb [8*2048][64] bf16, Vt [8][64][2048] bf16 -> out [8][2048][64] f32
// 2 waves/block; wave handles 16 q-rows. Strips paired (p, 127-p) for causal balance.
__global__ __launch_bounds__(128) void attn_k(
    const unsigned short* __restrict__ Qb, const unsigned short* __restrict__ Kb,
    const unsigned short* __restrict__ Vt, float* __restrict__ out)
{
    __shared__ __align__(16) unsigned short pl[2][16][40];  // P tile per wave, stride 80B
    const int tid = threadIdx.x;
    const int wid = tid >> 6, lane = tid & 63;
    const int lrow = lane & 15, g = lane >> 4;
    const int batch = blockIdx.x >> 6;
    const int p = blockIdx.x & 63;
    const int strip = wid ? (127 - p) : p;
    const int q_local = strip * 16;

    // Q fragments held in registers for the whole kv loop
    const unsigned short* Qrow = Qb + (batch * 2048 + q_local + lrow) * 64;
    bf16x8 qa0 = *(const bf16x8*)(Qrow + g * 8);
    bf16x8 qa1 = *(const bf16x8*)(Qrow + 32 + g * 8);

    const unsigned short* Kbase = Kb + batch * 2048 * 64;
    const unsigned short* Vbase = Vt + batch * 131072;

    f32x4 o[4];
#pragma unroll
    for (int n = 0; n < 4; n++) o[n] = (f32x4){0.f, 0.f, 0.f, 0.f};
    float m_run[4], l_run[4];
#pragma unroll
    for (int i = 0; i < 4; i++) { m_run[i] = -INFINITY; l_run[i] = 0.f; }

    const int nch = q_local / 32 + 1;
    for (int ch = 0; ch < nch; ch++) {
        const int kv0 = ch * 32;
        f32x4 s0 = (f32x4){0.f, 0.f, 0.f, 0.f};
        f32x4 s1 = (f32x4){0.f, 0.f, 0.f, 0.f};
        {
            const unsigned short* kr0 = Kbase + (kv0 + lrow) * 64;
            bf16x8 kb0 = *(const bf16x8*)(kr0 + g * 8);
            bf16x8 kb1 = *(const bf16x8*)(kr0 + 32 + g * 8);
            s0 = MFMA(qa0, kb0, s0);
            s0 = MFMA(qa1, kb1, s0);
            const unsigned short* kr1 = Kbase + (kv0 + 16 + lrow) * 64;
            bf16x8 kb2 = *(const bf16x8*)(kr1 + g * 8);
            bf16x8 kb3 = *(const bf16x8*)(kr1 + 32 + g * 8);
            s1 = MFMA(qa0, kb2, s1);
            s1 = MFMA(qa1, kb3, s1);
        }
        // online softmax: lane holds rows q_local+g*4+i, col kv0(+16)+lrow
        float e0[4], e1[4];
#pragma unroll
        for (int i = 0; i < 4; i++) {
            int qr = q_local + g * 4 + i;
            float v0 = s0[i] * 0.03125f;                // * E^-0.5
            float v1 = s1[i] * 0.03125f;
            if (kv0 + lrow > qr)      v0 = -INFINITY;   // causal mask
            if (kv0 + 16 + lrow > qr) v1 = -INFINITY;
            float mm = fmaxf(v0, v1);
#pragma unroll
            for (int msk = 1; msk < 16; msk <<= 1)
                mm = fmaxf(mm, __shfl_xor(mm, msk));
            float mn = fmaxf(m_run[i], mm);
            float c = __expf(m_run[i] - mn);
            m_run[i] = mn;
            e0[i] = __expf(v0 - mn);
            e1[i] = __expf(v1 - mn);
            float ts = e0[i] + e1[i];
#pragma unroll
            for (int msk = 1; msk < 16; msk <<= 1)
                ts += __shfl_xor(ts, msk);
            l_run[i] = l_run[i] * c + ts;
#pragma unroll
            for (int n = 0; n < 4; n++) o[n][i] *= c;
        }
        // P -> LDS (bf16), re-read as PV A-fragment
#pragma unroll
        for (int i = 0; i < 4; i++) {
            pl[wid][g * 4 + i][lrow]      = f2bf(e0[i]);
            pl[wid][g * 4 + i][16 + lrow] = f2bf(e1[i]);
        }
        asm volatile("s_waitcnt lgkmcnt(0)" ::: "memory");
        bf16x8 pa = *(const bf16x8*)&pl[wid][lrow][g * 8];
#pragma unroll
        for (int n = 0; n < 4; n++) {
            bf16x8 vb = *(const bf16x8*)(Vbase + (n * 16 + lrow) * 2048 + kv0 + g * 8);
            o[n] = MFMA(pa, vb, o[n]);
        }
    }

    float* ob = out + (batch * 2048 + q_local) * 64;
#pragma unroll
    for (int i = 0; i < 4; i++) {
        float inv = 1.f / l_run[i];
        int r = g * 4 + i;
#pragma unroll
        for (int n = 0; n < 4; n++)
            ob[r * 64 + n * 16 + lrow] = o[n][i] * inv;
    }
}

extern "C" void kernel_launch(void* const* d_in, const int* in_sizes, int n_in,
                              void* d_out, int out_size, void* d_ws, size_t ws_size,
                              hipStream_t stream) {
    const float* x  = (const float*)d_in[0];
    const float* Wk = (const float*)d_in[1];
    const float* Wq = (const float*)d_in[2];
    const float* Wv = (const float*)d_in[3];
    float* out = (float*)d_out;

    unsigned short* Wt = (unsigned short*)d_ws;        // [192][1024] bf16
    unsigned short* Kb = Wt + 3 * 65536;               // [16384][64]
    unsigned short* Qb = Kb + 16384 * 64;              // [16384][64]
    unsigned short* Vt = Qb + 16384 * 64;              // [8][64][2048]

    wtrans_k<<<768, 256, 0, stream>>>(Wk, Wq, Wv, Wt);
    qkv_k<<<512, 256, 0, stream>>>(x, Wt, Qb, Kb, Vt);
    attn_k<<<512, 128, 0, stream>>>(Qb, Kb, Vt, out);
}

// Round 2
// 64.301 us; speedup vs baseline: 1.5811x; 1.5811x over previous
//
#include <hip/hip_runtime.h>

typedef __attribute__((ext_vector_type(8))) short bf16x8;
typedef __attribute__((ext_vector_type(4))) float f32x4;
typedef __attribute__((ext_vector_type(4))) unsigned short u16x4;
typedef __attribute__((ext_vector_type(8))) unsigned short u16x8;

#define MFMA(a, b, c) __builtin_amdgcn_mfma_f32_16x16x32_bf16(a, b, c, 0, 0, 0)

static __device__ __forceinline__ unsigned short f2bf(float x) {
    union { float f; unsigned u; } v; v.f = x;
    unsigned r = v.u + 0x7fffu + ((v.u >> 16) & 1u);   // round-to-nearest-even
    return (unsigned short)(r >> 16);
}

// ---------------- Kernel 0: W [1024][64] f32 -> Wt [3][64][1024] bf16 ----------------
__global__ __launch_bounds__(256) void wtrans_k(
    const float* __restrict__ Wk, const float* __restrict__ Wq,
    const float* __restrict__ Wv, unsigned short* __restrict__ Wt)
{
    int id = blockIdx.x * 256 + threadIdx.x;          // < 3*65536
    int w = id >> 16, rem = id & 65535;
    int n = rem >> 10, k = rem & 1023;
    const float* W = (w == 0) ? Wk : (w == 1) ? Wq : Wv;
    Wt[id] = f2bf(W[k * 64 + n]);
}

// ---------------- Kernel 1: QKV projection ----------------
// x [16384][1024] f32, Wt [192][1024] bf16 (K,Q,V stacked)
// -> Kb [16384][64], Qb [16384][64], Vt [8][64][2048]   (all bf16)
__global__ __launch_bounds__(256) void qkv_k(
    const float* __restrict__ x, const unsigned short* __restrict__ Wt,
    unsigned short* __restrict__ Qb, unsigned short* __restrict__ Kb,
    unsigned short* __restrict__ Vt)
{
    __shared__ __align__(16) unsigned short xl[32][72];    // +8 pad: 2-way bank alias only
    __shared__ __align__(16) unsigned short wl[192][72];
    const int tid = threadIdx.x;
    const int wid = tid >> 6, lane = tid & 63;
    const int lrow = lane & 15, g = lane >> 4;
    const int mbase = blockIdx.x * 32;
    const int msrow = (wid & 1) * 16;        // wave's 16-row m-subtile
    const int ntbase = (wid >> 1) * 6;       // wave's 6 n-tiles (of 12)

    f32x4 acc[6];
#pragma unroll
    for (int j = 0; j < 6; j++) acc[j] = (f32x4){0.f, 0.f, 0.f, 0.f};

    for (int kc = 0; kc < 1024; kc += 64) {
#pragma unroll
        for (int rep = 0; rep < 2; rep++) {
            int flat = rep * 256 + tid;                 // 0..511
            int row = flat >> 4, c4 = (flat & 15) * 4;
            f32x4 v = *(const f32x4*)(x + (mbase + row) * 1024 + kc + c4);
            u16x4 h;
            h[0] = f2bf(v[0]); h[1] = f2bf(v[1]); h[2] = f2bf(v[2]); h[3] = f2bf(v[3]);
            *(u16x4*)&xl[row][c4] = h;
        }
#pragma unroll
        for (int rep = 0; rep < 6; rep++) {
            int flat = rep * 256 + tid;                 // 0..1535
            int n = flat >> 3, c = (flat & 7) * 8;
            *(u16x8*)&wl[n][c] = *(const u16x8*)(Wt + n * 1024 + kc + c);
        }
        __syncthreads();
#pragma unroll
        for (int ks = 0; ks < 2; ks++) {
            bf16x8 a = *(const bf16x8*)&xl[msrow + lrow][ks * 32 + g * 8];
#pragma unroll
            for (int j = 0; j < 6; j++) {
                bf16x8 b = *(const bf16x8*)&wl[(ntbase + j) * 16 + lrow][ks * 32 + g * 8];
                acc[j] = MFMA(a, b, acc[j]);
            }
        }
        __syncthreads();
    }

#pragma unroll
    for (int j = 0; j < 6; j++) {
        int nt = ntbase + j;
        int w = nt >> 2;                                // 0=K, 1=Q, 2=V
        int col = (nt & 3) * 16 + lrow;
        int r0 = mbase + msrow + g * 4;
        if (w == 2) {
            int b = r0 >> 11, t = r0 & 2047;
            u16x4 pv;
            pv[0] = f2bf(acc[j][0]); pv[1] = f2bf(acc[j][1]);
            pv[2] = f2bf(acc[j][2]); pv[3] = f2bf(acc[j][3]);
            *(u16x4*)(Vt + b * 131072 + col * 2048 + t) = pv;   // transposed V
        } else {
            unsigned short* dst = (w == 0) ? Kb : Qb;
#pragma unroll
            for (int i = 0; i < 4; i++)
                dst[(r0 + i) * 64 + col] = f2bf(acc[j][i]);
        }
    }
}

// ---------------- Kernel 2: causal flash attention (kv-split, in-LDS combine) ----------------
// Block = 8 waves, handles strip pair (p, 127-p): 65 chunks total, split among waves.
__global__ __launch_bounds__(512) void attn_k(
    const unsigned short* __restrict__ Qb, const unsigned short* __restrict__ Kb,
    const unsigned short* __restrict__ Vt, float* __restrict__ out)
{
    __shared__ __align__(16) unsigned short pl[8][16][40];  // P tile per wave
    __shared__ __align__(16) float po[8][16][68];           // o partials
    __shared__ float ml[8][16][2];                          // m,l partials
    const int tid = threadIdx.x;
    const int wid = tid >> 6, lane = tid & 63;
    const int lrow = lane & 15, g = lane >> 4;
    const int batch = blockIdx.x >> 6;
    const int p = blockIdx.x & 63;
    const int sA = p, sB = 127 - p;
    const int nA = sA / 2 + 1, nB = sB / 2 + 1;             // nA + nB == 65
    int wA = (nA * 8 + 32) / 65;
    wA = wA < 1 ? 1 : (wA > 7 ? 7 : wA);

    int strip, rr, gs;
    if (wid < wA) { strip = sA; rr = wid;       gs = wA; }
    else          { strip = sB; rr = wid - wA;  gs = 8 - wA; }
    const int nch = strip / 2 + 1;
    const int q_local = strip * 16;

    // Q fragments in registers for the whole kv loop
    const unsigned short* Qrow = Qb + (batch * 2048 + q_local + lrow) * 64;
    bf16x8 qa0 = *(const bf16x8*)(Qrow + g * 8);
    bf16x8 qa1 = *(const bf16x8*)(Qrow + 32 + g * 8);

    const unsigned short* Kbase = Kb + batch * 2048 * 64;
    const unsigned short* Vbase = Vt + batch * 131072;

    f32x4 o[4];
#pragma unroll
    for (int n = 0; n < 4; n++) o[n] = (f32x4){0.f, 0.f, 0.f, 0.f};
    float m_run[4], l_run[4];
#pragma unroll
    for (int i = 0; i < 4; i++) { m_run[i] = -INFINITY; l_run[i] = 0.f; }

    for (int cc = rr; cc < nch; cc += gs) {
        const int kv0 = cc * 32;
        f32x4 s0 = (f32x4){0.f, 0.f, 0.f, 0.f};
        f32x4 s1 = (f32x4){0.f, 0.f, 0.f, 0.f};
        {
            const unsigned short* kr0 = Kbase + (kv0 + lrow) * 64;
            bf16x8 kb0 = *(const bf16x8*)(kr0 + g * 8);
            bf16x8 kb1 = *(const bf16x8*)(kr0 + 32 + g * 8);
            s0 = MFMA(qa0, kb0, s0);
            s0 = MFMA(qa1, kb1, s0);
            const unsigned short* kr1 = Kbase + (kv0 + 16 + lrow) * 64;
            bf16x8 kb2 = *(const bf16x8*)(kr1 + g * 8);
            bf16x8 kb3 = *(const bf16x8*)(kr1 + 32 + g * 8);
            s1 = MFMA(qa0, kb2, s1);
            s1 = MFMA(qa1, kb3, s1);
        }
        // online softmax: lane holds rows q_local+g*4+i, col kv0(+16)+lrow
        float e0[4], e1[4];
#pragma unroll
        for (int i = 0; i < 4; i++) {
            int qr = q_local + g * 4 + i;
            float v0 = s0[i] * 0.03125f;                // * E^-0.5
            float v1 = s1[i] * 0.03125f;
            if (kv0 + lrow > qr)      v0 = -INFINITY;   // causal mask
            if (kv0 + 16 + lrow > qr) v1 = -INFINITY;
            float mm = fmaxf(v0, v1);
#pragma unroll
            for (int msk = 1; msk < 16; msk <<= 1)
                mm = fmaxf(mm, __shfl_xor(mm, msk));
            float mn = fmaxf(m_run[i], mm);
            float sc = __expf(m_run[i] - mn);
            m_run[i] = mn;
            e0[i] = __expf(v0 - mn);
            e1[i] = __expf(v1 - mn);
            float ts = e0[i] + e1[i];
#pragma unroll
            for (int msk = 1; msk < 16; msk <<= 1)
                ts += __shfl_xor(ts, msk);
            l_run[i] = l_run[i] * sc + ts;
#pragma unroll
            for (int n = 0; n < 4; n++) o[n][i] *= sc;
        }
        // P -> LDS (bf16), re-read as PV A-fragment
#pragma unroll
        for (int i = 0; i < 4; i++) {
            pl[wid][g * 4 + i][lrow]      = f2bf(e0[i]);
            pl[wid][g * 4 + i][16 + lrow] = f2bf(e1[i]);
        }
        asm volatile("s_waitcnt lgkmcnt(0)" ::: "memory");
        bf16x8 pa = *(const bf16x8*)&pl[wid][lrow][g * 8];
#pragma unroll
        for (int n = 0; n < 4; n++) {
            bf16x8 vb = *(const bf16x8*)(Vbase + (n * 16 + lrow) * 2048 + kv0 + g * 8);
            o[n] = MFMA(pa, vb, o[n]);
        }
    }

    // write per-wave partials
#pragma unroll
    for (int i = 0; i < 4; i++) {
        int row = g * 4 + i;
#pragma unroll
        for (int n = 0; n < 4; n++) po[wid][row][n * 16 + lrow] = o[n][i];
        if (lrow == 0) { ml[wid][row][0] = m_run[i]; ml[wid][row][1] = l_run[i]; }
    }
    __syncthreads();

    // combine: 32 output rows x 64 cols; waves 0-3 -> strip A rows, waves 4-7 -> strip B
    {
        int row_id = tid >> 4;            // 0..31
        int cn = (tid & 15) * 4;
        int isB = row_id >> 4;
        int row = row_id & 15;
        int w0 = isB ? wA : 0;
        int w1 = isB ? 8 : wA;
        int strip_o = isB ? sB : sA;
        float M = -INFINITY;
        for (int w = w0; w < w1; w++) M = fmaxf(M, ml[w][row][0]);
        float L = 0.f;
        f32x4 O = (f32x4){0.f, 0.f, 0.f, 0.f};
        for (int w = w0; w < w1; w++) {
            float sc = __expf(ml[w][row][0] - M);
            L += ml[w][row][1] * sc;
            f32x4 v = *(const f32x4*)&po[w][row][cn];
            O[0] += v[0] * sc; O[1] += v[1] * sc;
            O[2] += v[2] * sc; O[3] += v[3] * sc;
        }
        float inv = 1.f / L;
        f32x4 res;
        res[0] = O[0] * inv; res[1] = O[1] * inv;
        res[2] = O[2] * inv; res[3] = O[3] * inv;
        *(f32x4*)(out + (batch * 2048 + strip_o * 16 + row) * 64 + cn) = res;
    }
}

extern "C" void kernel_launch(void* const* d_in, const int* in_sizes, int n_in,
                              void* d_out, int out_size, void* d_ws, size_t ws_size,
                              hipStream_t stream) {
    const float* x  = (const float*)d_in[0];
    const float* Wk = (const float*)d_in[1];
    const float* Wq = (const float*)d_in[2];
    const float* Wv = (const float*)d_in[3];
    float* out = (float*)d_out;

    unsigned short* Wt = (unsigned short*)d_ws;        // [192][1024] bf16
    unsigned short* Kb = Wt + 3 * 65536;               // [16384][64]
    unsigned short* Qb = Kb + 16384 * 64;              // [16384][64]
    unsigned short* Vt = Qb + 16384 * 64;              // [8][64][2048]

    wtrans_k<<<768, 256, 0, stream>>>(Wk, Wq, Wv, Wt);
    qkv_k<<<512, 256, 0, stream>>>(x, Wt, Qb, Kb, Vt);
    attn_k<<<512, 512, 0, stream>>>(Qb, Kb, Vt, out);
}